// Round 2
// baseline (130.265 us; speedup 1.0000x reference)
//
#include <hip/hip_runtime.h>

#define N_SOURCE   100000
#define N_TARGET   4096
#define SOURCE_DIM 512
#define EMBED_DIM  32
#define TARGET_DIM 16

// ---------------------------------------------------------------------------
// Kernel 0: M = embed @ weight   [SOURCE_DIM][TARGET_DIM]  (folds both GEMMs)
// ---------------------------------------------------------------------------
__global__ __launch_bounds__(256)
void k_embed_weight(const float* __restrict__ embed,   // [512][32]
                    const float* __restrict__ weight,  // [32][16]
                    float* __restrict__ M) {           // [512][16]
    __shared__ float wlds[EMBED_DIM * TARGET_DIM];     // 512 floats
    int tid = threadIdx.x;
    for (int i = tid; i < EMBED_DIM * TARGET_DIM; i += 256)
        wlds[i] = weight[i];
    __syncthreads();

    int idx = blockIdx.x * 256 + tid;                  // 0..8191
    if (idx < SOURCE_DIM * TARGET_DIM) {
        int k = idx >> 4;        // embed row
        int o = idx & 15;        // output col
        float s = 0.f;
        #pragma unroll
        for (int j = 0; j < EMBED_DIM; ++j)
            s += embed[k * EMBED_DIM + j] * wlds[j * TARGET_DIM + o];
        M[idx] = s;
    }
}

// ---------------------------------------------------------------------------
// Kernel 1: y[r][:] = (source_feat[r][:] @ M) / x_norm[r]     [N_SOURCE][16]
// One thread per row, 16 f32 accumulators. A read as 8xfloat4 (one 128B line)
// per k-block, double-buffered 2 blocks deep. M reads are wave-uniform
// (loop-var indices only) -> scalar s_load pipe, zero VALU/LDS cost.
// ---------------------------------------------------------------------------

// 16 FMAs for one k, scalar a times M[k][0..15] (4 uniform float4 loads)
#define FMA_K(AV, KIDX)                                                     \
    do {                                                                    \
        const float4 m0_ = M4[(KIDX) * 4 + 0];                              \
        const float4 m1_ = M4[(KIDX) * 4 + 1];                              \
        const float4 m2_ = M4[(KIDX) * 4 + 2];                              \
        const float4 m3_ = M4[(KIDX) * 4 + 3];                              \
        const float a_ = (AV);                                              \
        acc[0]  += a_ * m0_.x; acc[1]  += a_ * m0_.y;                       \
        acc[2]  += a_ * m0_.z; acc[3]  += a_ * m0_.w;                       \
        acc[4]  += a_ * m1_.x; acc[5]  += a_ * m1_.y;                       \
        acc[6]  += a_ * m1_.z; acc[7]  += a_ * m1_.w;                       \
        acc[8]  += a_ * m2_.x; acc[9]  += a_ * m2_.y;                       \
        acc[10] += a_ * m2_.z; acc[11] += a_ * m2_.w;                       \
        acc[12] += a_ * m3_.x; acc[13] += a_ * m3_.y;                       \
        acc[14] += a_ * m3_.z; acc[15] += a_ * m3_.w;                       \
    } while (0)

// consume one k-block of 8 float4 (32 k's) starting at k = KB*32
#define FMA_BLOCK(BUF, KB)                                                  \
    do {                                                                    \
        _Pragma("unroll")                                                   \
        for (int i_ = 0; i_ < 8; ++i_) {                                    \
            int k0_ = (KB) * 32 + i_ * 4;                                   \
            FMA_K(BUF[i_].x, k0_ + 0);                                      \
            FMA_K(BUF[i_].y, k0_ + 1);                                      \
            FMA_K(BUF[i_].z, k0_ + 2);                                      \
            FMA_K(BUF[i_].w, k0_ + 3);                                      \
        }                                                                   \
    } while (0)

__global__ __launch_bounds__(256)
void k_gemm_y(const float* __restrict__ A,       // source_feat [N_SOURCE][512]
              const float* __restrict__ xnorm,   // [N_SOURCE]
              const float* __restrict__ M,       // [512][16]
              float* __restrict__ y) {           // [N_SOURCE][16]
    int r = blockIdx.x * 256 + threadIdx.x;
    bool valid = r < N_SOURCE;
    int rr = valid ? r : N_SOURCE - 1;           // clamp, discard at store

    const float4* __restrict__ A4 = (const float4*)(A + (size_t)rr * SOURCE_DIM);
    const float4* __restrict__ M4 = (const float4*)M;   // wave-uniform reads

    float acc[16];
    #pragma unroll
    for (int c = 0; c < 16; ++c) acc[c] = 0.f;

    float4 bufA[8], bufB[8];
    #pragma unroll
    for (int i = 0; i < 8; ++i) bufA[i] = A4[i];          // k-block 0

    // 16 k-blocks of 32 floats (128B line each); 2 per iteration, dbuf'd
    #pragma unroll 1
    for (int it = 0; it < 8; ++it) {
        int kb = it * 2;
        // prefetch k-block kb+1 while computing kb
        if (kb + 1 < 16) {
            #pragma unroll
            for (int i = 0; i < 8; ++i) bufB[i] = A4[(kb + 1) * 8 + i];
        }
        FMA_BLOCK(bufA, kb);
        if (kb + 2 < 16) {
            #pragma unroll
            for (int i = 0; i < 8; ++i) bufA[i] = A4[(kb + 2) * 8 + i];
        }
        if (kb + 1 < 16) FMA_BLOCK(bufB, kb + 1);
    }

    if (valid) {
        float inv = 1.0f / xnorm[r];
        float4* __restrict__ Y4 = (float4*)(y + (size_t)r * TARGET_DIM);
        Y4[0] = make_float4(acc[0]  * inv, acc[1]  * inv, acc[2]  * inv, acc[3]  * inv);
        Y4[1] = make_float4(acc[4]  * inv, acc[5]  * inv, acc[6]  * inv, acc[7]  * inv);
        Y4[2] = make_float4(acc[8]  * inv, acc[9]  * inv, acc[10] * inv, acc[11] * inv);
        Y4[3] = make_float4(acc[12] * inv, acc[13] * inv, acc[14] * inv, acc[15] * inv);
    }
}

// ---------------------------------------------------------------------------
// Kernel 2: out[t][:] = mean over edges of y[src[e]][:]
// one block (256 thr) per target; 64 edge slots x 4 lanes (float4 each);
// wave butterfly over slot bits, then tiny LDS cross-wave reduce.
// ---------------------------------------------------------------------------
__global__ __launch_bounds__(256)
void k_gather_mean(const float* __restrict__ y,    // [N_SOURCE][16]
                   const int*   __restrict__ src,  // edge_index row 0
                   const int*   __restrict__ rl,   // range_list [N_TARGET][2]
                   float* __restrict__ out) {      // [N_TARGET][16]
    int t     = blockIdx.x;
    int tid   = threadIdx.x;
    int start = rl[2 * t];
    int end   = rl[2 * t + 1];

    int slot = tid >> 2;   // 0..63
    int sub  = tid & 3;    // which float4 of the 16-float row

    float ax = 0.f, ay = 0.f, az = 0.f, aw = 0.f;
    for (int e = start + slot; e < end; e += 64) {
        int s = src[e];
        float4 v = *(const float4*)&y[(size_t)s * TARGET_DIM + sub * 4];
        ax += v.x; ay += v.y; az += v.z; aw += v.w;
    }

    // butterfly over slot bits within the wave (lane bits 2..5)
    #pragma unroll
    for (int m = 4; m <= 32; m <<= 1) {
        ax += __shfl_xor(ax, m);
        ay += __shfl_xor(ay, m);
        az += __shfl_xor(az, m);
        aw += __shfl_xor(aw, m);
    }

    __shared__ float red[4][16];
    int wid  = tid >> 6;
    int lane = tid & 63;
    if (lane < 4) {
        red[wid][lane * 4 + 0] = ax;
        red[wid][lane * 4 + 1] = ay;
        red[wid][lane * 4 + 2] = az;
        red[wid][lane * 4 + 3] = aw;
    }
    __syncthreads();

    if (tid < TARGET_DIM) {
        float s = red[0][tid] + red[1][tid] + red[2][tid] + red[3][tid];
        float deg = (float)(end - start);
        deg = deg > 1.f ? deg : 1.f;
        out[t * TARGET_DIM + tid] = s / deg;
    }
}

// ---------------------------------------------------------------------------
extern "C" void kernel_launch(void* const* d_in, const int* in_sizes, int n_in,
                              void* d_out, int out_size, void* d_ws, size_t ws_size,
                              hipStream_t stream) {
    const float* source_feat = (const float*)d_in[0];  // [100000][512]
    const float* embed       = (const float*)d_in[1];  // [512][32]
    const float* weight      = (const float*)d_in[2];  // [32][16]
    const int*   edge_src    = (const int*)d_in[3];    // edge_index[0][:] (row 0)
    const int*   range_list  = (const int*)d_in[4];    // [4096][2]
    const float* x_norm      = (const float*)d_in[5];  // [100000]

    float* out = (float*)d_out;
    float* M   = (float*)d_ws;                          // 32 KB
    float* y   = (float*)((char*)d_ws + 32768);         // 6.4 MB

    k_embed_weight<<<32, 256, 0, stream>>>(embed, weight, M);

    int nblk = (N_SOURCE + 255) / 256;                  // 391
    k_gemm_y<<<nblk, 256, 0, stream>>>(source_feat, x_norm, M, y);

    k_gather_mean<<<N_TARGET, 256, 0, stream>>>(y, edge_src, range_list, out);
}

// Round 3
// 83.567 us; speedup vs baseline: 1.5588x; 1.5588x over previous
//
#include <hip/hip_runtime.h>
#include <hip/hip_bf16.h>

#define N_SOURCE   100000
#define N_TARGET   4096
#define SOURCE_DIM 512
#define EMBED_DIM  32
#define TARGET_DIM 16

// ---------------------------------------------------------------------------
// Kernel 0: M = embed @ weight   [SOURCE_DIM][TARGET_DIM]  (folds both GEMMs)
// ---------------------------------------------------------------------------
__global__ __launch_bounds__(256)
void k_embed_weight(const float* __restrict__ embed,   // [512][32]
                    const float* __restrict__ weight,  // [32][16]
                    float* __restrict__ M) {           // [512][16]
    __shared__ float wlds[EMBED_DIM * TARGET_DIM];     // 512 floats
    int tid = threadIdx.x;
    for (int i = tid; i < EMBED_DIM * TARGET_DIM; i += 256)
        wlds[i] = weight[i];
    __syncthreads();

    int idx = blockIdx.x * 256 + tid;                  // 0..8191
    if (idx < SOURCE_DIM * TARGET_DIM) {
        int k = idx >> 4;        // embed row
        int o = idx & 15;        // output col
        float s = 0.f;
        #pragma unroll
        for (int j = 0; j < EMBED_DIM; ++j)
            s += embed[k * EMBED_DIM + j] * wlds[j * TARGET_DIM + o];
        M[idx] = s;
    }
}

// ---------------------------------------------------------------------------
// Kernel 1: y[r][:] = bf16( (source_feat[r][:] @ M) / x_norm[r] )
// One thread per row, 16 f32 accumulators. A read direct from global as
// float4 (prefetch depth 3). M staged in LDS; all 64 lanes read the SAME
// address -> broadcast (no bank conflict, ~1 data beat per b128).
// ---------------------------------------------------------------------------
__global__ __launch_bounds__(256)
void k_gemm_y(const float* __restrict__ A,       // source_feat [N_SOURCE][512]
              const float* __restrict__ xnorm,   // [N_SOURCE]
              const float* __restrict__ Mg,      // [512][16]
              ushort* __restrict__ y) {          // [N_SOURCE][16] bf16
    __shared__ float Ml[SOURCE_DIM * TARGET_DIM];  // 32 KB
    int tid = threadIdx.x;

    // stage M: 2048 float4, 8 per thread, coalesced
    #pragma unroll
    for (int i = 0; i < 8; ++i) {
        int f = tid + 256 * i;
        *(float4*)&Ml[f * 4] = ((const float4*)Mg)[f];
    }
    __syncthreads();

    int r  = blockIdx.x * 256 + tid;
    int rr = r < N_SOURCE ? r : N_SOURCE - 1;      // clamp, discard at store
    const float4* __restrict__ A4 = (const float4*)(A + (size_t)rr * SOURCE_DIM);

    float acc[16];
    #pragma unroll
    for (int i = 0; i < 16; ++i) acc[i] = 0.f;

    // prefetch depth 3 (~48 B/lane in flight -> ~12 KB/CU at 6 waves/CU)
    float4 b0 = A4[0], b1 = A4[1], b2 = A4[2];

    #pragma unroll 4
    for (int c = 0; c < 128; ++c) {                // 4 k's per iteration
        float4 cur = b0;
        b0 = b1; b1 = b2;
        b2 = A4[c + 3 < 128 ? c + 3 : 127];        // clamped, branch-free
        int k0 = c * 4;
        #pragma unroll
        for (int kk = 0; kk < 4; ++kk) {
            float av = (kk == 0) ? cur.x : (kk == 1) ? cur.y
                     : (kk == 2) ? cur.z : cur.w;
            const float4 m0 = *(const float4*)&Ml[(k0 + kk) * 16 + 0];
            const float4 m1 = *(const float4*)&Ml[(k0 + kk) * 16 + 4];
            const float4 m2 = *(const float4*)&Ml[(k0 + kk) * 16 + 8];
            const float4 m3 = *(const float4*)&Ml[(k0 + kk) * 16 + 12];
            acc[0]  += av * m0.x; acc[1]  += av * m0.y;
            acc[2]  += av * m0.z; acc[3]  += av * m0.w;
            acc[4]  += av * m1.x; acc[5]  += av * m1.y;
            acc[6]  += av * m1.z; acc[7]  += av * m1.w;
            acc[8]  += av * m2.x; acc[9]  += av * m2.y;
            acc[10] += av * m2.z; acc[11] += av * m2.w;
            acc[12] += av * m3.x; acc[13] += av * m3.y;
            acc[14] += av * m3.z; acc[15] += av * m3.w;
        }
    }

    if (r < N_SOURCE) {
        float inv = 1.0f / xnorm[r];
        uint p[8];
        #pragma unroll
        for (int i = 0; i < 8; ++i) {
            __hip_bfloat16 lo = __float2bfloat16(acc[2 * i]     * inv);
            __hip_bfloat16 hi = __float2bfloat16(acc[2 * i + 1] * inv);
            p[i] = (uint)*(ushort*)&lo | ((uint)*(ushort*)&hi << 16);
        }
        uint4* Y = (uint4*)(y + (size_t)r * TARGET_DIM);   // 32 B/row
        Y[0] = make_uint4(p[0], p[1], p[2], p[3]);
        Y[1] = make_uint4(p[4], p[5], p[6], p[7]);
    }
}

// ---------------------------------------------------------------------------
// Kernel 2: out[t][:] = mean over edges of y[src[e]][:]   (y is bf16)
// One block per target. 2 lanes per edge (16 B bf16 each), 128 edge slots.
// Index prefetched one step ahead to break the idx->gather chain.
// ---------------------------------------------------------------------------
__global__ __launch_bounds__(256)
void k_gather_mean(const ushort* __restrict__ y,   // [N_SOURCE][16] bf16
                   const int*    __restrict__ src, // edge sources
                   const int*    __restrict__ rl,  // range_list [N_TARGET][2]
                   float* __restrict__ out) {      // [N_TARGET][16] f32
    int t     = blockIdx.x;
    int tid   = threadIdx.x;
    int start = rl[2 * t];
    int end   = rl[2 * t + 1];

    int slot = tid >> 1;          // 0..127 across the block
    int sub  = tid & 1;           // which 16B half of the 32B row

    float a[8];
    #pragma unroll
    for (int i = 0; i < 8; ++i) a[i] = 0.f;

    int e = start + slot;
    int s_cur = (e < end) ? src[e] : 0;
    while (e < end) {
        int e2 = e + 128;
        int s_nxt = (e2 < end) ? src[e2] : 0;
        uint4 v = *(const uint4*)(y + (size_t)s_cur * TARGET_DIM + sub * 8);
        const uint w[4] = {v.x, v.y, v.z, v.w};
        #pragma unroll
        for (int i = 0; i < 4; ++i) {
            uint lo = w[i] << 16;
            uint hi = w[i] & 0xffff0000u;
            a[2 * i]     += *(float*)&lo;
            a[2 * i + 1] += *(float*)&hi;
        }
        e = e2; s_cur = s_nxt;
    }

    // butterfly over slot bits within the wave (lane bits 1..5)
    #pragma unroll
    for (int m = 2; m <= 32; m <<= 1) {
        #pragma unroll
        for (int i = 0; i < 8; ++i) a[i] += __shfl_xor(a[i], m);
    }

    __shared__ float red[4][16];
    int wid  = tid >> 6;
    int lane = tid & 63;
    if (lane < 2) {               // lane0 = sub0 half, lane1 = sub1 half
        #pragma unroll
        for (int i = 0; i < 8; ++i) red[wid][lane * 8 + i] = a[i];
    }
    __syncthreads();

    if (tid < TARGET_DIM) {
        float s = red[0][tid] + red[1][tid] + red[2][tid] + red[3][tid];
        float deg = (float)(end - start);
        deg = deg > 1.f ? deg : 1.f;
        out[t * TARGET_DIM + tid] = s / deg;
    }
}

// ---------------------------------------------------------------------------
extern "C" void kernel_launch(void* const* d_in, const int* in_sizes, int n_in,
                              void* d_out, int out_size, void* d_ws, size_t ws_size,
                              hipStream_t stream) {
    const float* source_feat = (const float*)d_in[0];  // [100000][512]
    const float* embed       = (const float*)d_in[1];  // [512][32]
    const float* weight      = (const float*)d_in[2];  // [32][16]
    const int*   edge_src    = (const int*)d_in[3];    // edge_index[0][:]
    const int*   range_list  = (const int*)d_in[4];    // [4096][2]
    const float* x_norm      = (const float*)d_in[5];  // [100000]

    float*  out = (float*)d_out;
    float*  M   = (float*)d_ws;                         // 32 KB
    ushort* y   = (ushort*)((char*)d_ws + 32768);       // 3.2 MB bf16

    k_embed_weight<<<32, 256, 0, stream>>>(embed, weight, M);

    int nblk = (N_SOURCE + 255) / 256;                  // 391
    k_gemm_y<<<nblk, 256, 0, stream>>>(source_feat, x_norm, M, y);

    k_gather_mean<<<N_TARGET, 256, 0, stream>>>(y, edge_src, range_list, out);
}

// Round 4
// 71.477 us; speedup vs baseline: 1.8225x; 1.1691x over previous
//
#include <hip/hip_runtime.h>
#include <hip/hip_bf16.h>

#define N_SOURCE   100000
#define N_TARGET   4096
#define SOURCE_DIM 512
#define EMBED_DIM  32
#define TARGET_DIM 16
#define NTILES     (N_SOURCE / 16)   // 6250 row-tiles of 16
#define TILES_PER_WAVE 2

typedef __attribute__((ext_vector_type(8))) short short8;   // 8 bf16 (4 VGPR)
typedef __attribute__((ext_vector_type(4))) float f32x4;    // MFMA accumulator

static __device__ __forceinline__ ushort f2bf(float f) {
    __hip_bfloat16 h = __float2bfloat16(f);   // RNE
    return *(ushort*)&h;
}

// ---------------------------------------------------------------------------
// Kernel 0: Mt = bf16( (embed @ weight)^T )   [16][512]  (folds both GEMMs)
// ---------------------------------------------------------------------------
__global__ __launch_bounds__(256)
void k_embed_weight(const float* __restrict__ embed,   // [512][32]
                    const float* __restrict__ weight,  // [32][16]
                    ushort* __restrict__ Mt) {         // [16][512] bf16
    __shared__ float wlds[EMBED_DIM * TARGET_DIM];
    int tid = threadIdx.x;
    for (int i = tid; i < EMBED_DIM * TARGET_DIM; i += 256)
        wlds[i] = weight[i];
    __syncthreads();

    int idx = blockIdx.x * 256 + tid;                  // 0..8191
    if (idx < SOURCE_DIM * TARGET_DIM) {
        int k = idx >> 4;        // embed row (K index)
        int o = idx & 15;        // output col
        float s = 0.f;
        #pragma unroll
        for (int j = 0; j < EMBED_DIM; ++j)
            s += embed[k * EMBED_DIM + j] * wlds[j * TARGET_DIM + o];
        Mt[o * SOURCE_DIM + k] = f2bf(s);              // transposed store
    }
}

// ---------------------------------------------------------------------------
// Kernel 1: y[r][:] = bf16( (source_feat[r][:] @ M) / x_norm[r] )  via MFMA.
// One wave = one 16-row tile per step; B (Mt) preloaded into 64 VGPRs; A
// streamed from global (2 dwordx4/lane/chunk), cvt f32->bf16 in-reg.
// A-frag: lane holds A[lane&15][kk*32 + (lane>>4)*8 + i]
// B-frag: lane holds B[kk*32 + (lane>>4)*8 + i][lane&15]  (Mt rows contiguous)
// C/D   : col = lane&15, row = (lane>>4)*4 + reg          (m89-verified)
// ---------------------------------------------------------------------------
__global__ __launch_bounds__(256, 2)
void k_gemm_y(const float*  __restrict__ A,      // source_feat [N_SOURCE][512]
              const float*  __restrict__ xnorm,  // [N_SOURCE]
              const ushort* __restrict__ Mt,     // [16][512] bf16
              ushort*       __restrict__ y) {    // [N_SOURCE][16] bf16
    int tid  = threadIdx.x;
    int wave = tid >> 6;
    int lane = tid & 63;
    int n    = lane & 15;     // A row within tile / B col / C col
    int g    = lane >> 4;     // k-group 0..3

    // preload B fragments (whole Mt: 16 chunks x 16B/lane, L2-hot)
    short8 bfrag[16];
    #pragma unroll
    for (int kk = 0; kk < 16; ++kk)
        bfrag[kk] = *(const short8*)(Mt + n * SOURCE_DIM + kk * 32 + g * 8);

    int tbase = blockIdx.x * (4 * TILES_PER_WAVE) + wave * TILES_PER_WAVE;

    #pragma unroll
    for (int t = 0; t < TILES_PER_WAVE; ++t) {
        int tile = tbase + t;
        if (tile >= NTILES) break;
        int row0 = tile * 16;
        const float* Arow = A + (size_t)(row0 + n) * SOURCE_DIM + g * 8;

        f32x4 acc = {0.f, 0.f, 0.f, 0.f};
        #pragma unroll
        for (int kk = 0; kk < 16; ++kk) {
            float4 a0 = *(const float4*)(Arow + kk * 32);
            float4 a1 = *(const float4*)(Arow + kk * 32 + 4);
            short8 af;
            af[0] = (short)f2bf(a0.x); af[1] = (short)f2bf(a0.y);
            af[2] = (short)f2bf(a0.z); af[3] = (short)f2bf(a0.w);
            af[4] = (short)f2bf(a1.x); af[5] = (short)f2bf(a1.y);
            af[6] = (short)f2bf(a1.z); af[7] = (short)f2bf(a1.w);
            acc = __builtin_amdgcn_mfma_f32_16x16x32_bf16(af, bfrag[kk], acc, 0, 0, 0);
        }

        // epilogue: lane holds C[g*4 + r][n], r = 0..3
        int m0 = g * 4;
        float4 xn = *(const float4*)(xnorm + row0 + m0);   // 16B aligned
        const float xr[4] = {xn.x, xn.y, xn.z, xn.w};
        #pragma unroll
        for (int r = 0; r < 4; ++r)
            y[(size_t)(row0 + m0 + r) * TARGET_DIM + n] = f2bf(acc[r] / xr[r]);
    }
}

// ---------------------------------------------------------------------------
// Kernel 2: out[t][:] = mean over edges of y[src[e]][:]   (y is bf16)
// One block per target. 2 lanes per edge (16 B bf16 each), 128 edge slots.
// ---------------------------------------------------------------------------
__global__ __launch_bounds__(256)
void k_gather_mean(const ushort* __restrict__ y,   // [N_SOURCE][16] bf16
                   const int*    __restrict__ src, // edge sources
                   const int*    __restrict__ rl,  // range_list [N_TARGET][2]
                   float* __restrict__ out) {      // [N_TARGET][16] f32
    int t     = blockIdx.x;
    int tid   = threadIdx.x;
    int start = rl[2 * t];
    int end   = rl[2 * t + 1];

    int slot = tid >> 1;          // 0..127 across the block
    int sub  = tid & 1;           // which 16B half of the 32B row

    float a[8];
    #pragma unroll
    for (int i = 0; i < 8; ++i) a[i] = 0.f;

    int e = start + slot;
    int s_cur = (e < end) ? src[e] : 0;
    while (e < end) {
        int e2 = e + 128;
        int s_nxt = (e2 < end) ? src[e2] : 0;
        uint4 v = *(const uint4*)(y + (size_t)s_cur * TARGET_DIM + sub * 8);
        const uint w[4] = {v.x, v.y, v.z, v.w};
        #pragma unroll
        for (int i = 0; i < 4; ++i) {
            uint lo = w[i] << 16;
            uint hi = w[i] & 0xffff0000u;
            a[2 * i]     += *(float*)&lo;
            a[2 * i + 1] += *(float*)&hi;
        }
        e = e2; s_cur = s_nxt;
    }

    #pragma unroll
    for (int m = 2; m <= 32; m <<= 1) {
        #pragma unroll
        for (int i = 0; i < 8; ++i) a[i] += __shfl_xor(a[i], m);
    }

    __shared__ float red[4][16];
    int wid  = tid >> 6;
    int lane = tid & 63;
    if (lane < 2) {
        #pragma unroll
        for (int i = 0; i < 8; ++i) red[wid][lane * 8 + i] = a[i];
    }
    __syncthreads();

    if (tid < TARGET_DIM) {
        float s = red[0][tid] + red[1][tid] + red[2][tid] + red[3][tid];
        float deg = (float)(end - start);
        deg = deg > 1.f ? deg : 1.f;
        out[t * TARGET_DIM + tid] = s / deg;
    }
}

// ---------------------------------------------------------------------------
extern "C" void kernel_launch(void* const* d_in, const int* in_sizes, int n_in,
                              void* d_out, int out_size, void* d_ws, size_t ws_size,
                              hipStream_t stream) {
    const float* source_feat = (const float*)d_in[0];  // [100000][512]
    const float* embed       = (const float*)d_in[1];  // [512][32]
    const float* weight      = (const float*)d_in[2];  // [32][16]
    const int*   edge_src    = (const int*)d_in[3];    // edge_index[0][:]
    const int*   range_list  = (const int*)d_in[4];    // [4096][2]
    const float* x_norm      = (const float*)d_in[5];  // [100000]

    float*  out = (float*)d_out;
    ushort* Mt  = (ushort*)d_ws;                        // 16 KB bf16 [16][512]
    ushort* y   = (ushort*)((char*)d_ws + 16384);       // 3.2 MB bf16

    k_embed_weight<<<32, 256, 0, stream>>>(embed, weight, Mt);

    int nblk = (NTILES + 4 * TILES_PER_WAVE - 1) / (4 * TILES_PER_WAVE);  // 782
    k_gemm_y<<<nblk, 256, 0, stream>>>(source_feat, x_norm, Mt, y);

    k_gather_mean<<<N_TARGET, 256, 0, stream>>>(y, edge_src, range_list, out);
}